// Round 1
// baseline (940.248 us; speedup 1.0000x reference)
//
#include <hip/hip_runtime.h>
#include <hip/hip_fp16.h>

#define N_NODES 50000
#define N_EDGES 1600000
#define FEAT    1536
#define HID     200
#define HIDP    208      // padded to 13*16 for MFMA-N
#define HID2    416      // both branches, padded
#define KDIM    768

typedef _Float16 half8 __attribute__((ext_vector_type(8)));
typedef _Float16 half4 __attribute__((ext_vector_type(4)));
typedef float   float4v __attribute__((ext_vector_type(4)));

// ---------------- prep: W1 -> fp16 transposed+padded, b1/W2 combined+padded ----
__global__ void prep_kernel(const float* __restrict__ W1a, const float* __restrict__ b1a,
                            const float* __restrict__ W2a,
                            const float* __restrict__ W1b, const float* __restrict__ b1b,
                            const float* __restrict__ W2b,
                            _Float16* __restrict__ Wht, float* __restrict__ b1comb,
                            float* __restrict__ W2comb) {
  int i = blockIdx.x * 256 + threadIdx.x;
  if (i < 2 * HIDP * KDIM) {
    int br = i / (HIDP * KDIM);
    int r  = i % (HIDP * KDIM);
    int n = r / KDIM, k = r % KDIM;
    const float* W = br ? W1b : W1a;             // (768,200) row-major
    Wht[i] = (n < HID) ? (_Float16)W[k * HID + n] : (_Float16)0.0f;  // Wht[br][n][k]
  }
  if (i < HID2) {
    int br = i / HIDP, c = i % HIDP;
    const float* b  = br ? b1b : b1a;
    const float* W2 = br ? W2b : W2a;            // (200,2) row-major
    bool ok = (c < HID);
    b1comb[i]       = ok ? b[c]        : 0.0f;
    W2comb[2*i + 0] = ok ? W2[c*2 + 0] : 0.0f;
    W2comb[2*i + 1] = ok ? W2[c*2 + 1] : 0.0f;
  }
}

// ---------------- CSR build: histogram ----------------
__global__ void hist_kernel(const int* __restrict__ dst, int* __restrict__ cnt) {
  int i = blockIdx.x * 256 + threadIdx.x;
  if (i < N_EDGES) atomicAdd(&cnt[dst[i]], 1);
}

// ---------------- CSR build: exclusive scan over 50000 counts ----------------
__global__ __launch_bounds__(1024) void scan_kernel(const int* __restrict__ cnt,
                                                    int* __restrict__ row_ptr) {
  __shared__ int s[1024];
  const int tid = threadIdx.x;
  const int base = tid * 49;                     // 1024*49 = 50176 >= 50000
  int sum = 0;
  for (int j = 0; j < 49; ++j) {
    int idx = base + j;
    if (idx < N_NODES) sum += cnt[idx];
  }
  s[tid] = sum;
  __syncthreads();
  for (int off = 1; off < 1024; off <<= 1) {
    int add = (tid >= off) ? s[tid - off] : 0;
    __syncthreads();
    s[tid] += add;
    __syncthreads();
  }
  int run = s[tid] - sum;                        // exclusive prefix of this chunk
  for (int j = 0; j < 49; ++j) {
    int idx = base + j;
    if (idx < N_NODES) { row_ptr[idx] = run; run += cnt[idx]; }
  }
  if (tid == 1023) row_ptr[N_NODES] = s[1023];
}

// ---------------- CSR build: permute edges into dst-sorted order ----------------
__global__ void permute_kernel(const int* __restrict__ src, const int* __restrict__ dst,
                               const float* __restrict__ w, const int* __restrict__ row_ptr,
                               int* __restrict__ cnt2, int2* __restrict__ ssw) {
  int i = blockIdx.x * 256 + threadIdx.x;
  if (i < N_EDGES) {
    int d = dst[i];
    int pos = row_ptr[d] + atomicAdd(&cnt2[d], 1);
    ssw[pos] = make_int2(src[i], __float_as_int(w[i]));
  }
}

// ---------------- GEMM1: h_pre = fp16( x_half @ W1 ), both branches ----------------
// grid (391, 2), block 256. Tile 128(M) x 208(N) x 32(K). Wave-tile 32x208.
__global__ __launch_bounds__(256, 2) void gemm1_kernel(const float* __restrict__ x,
    const _Float16* __restrict__ Wht, _Float16* __restrict__ hpre) {
  const int m0 = blockIdx.x * 128;
  const int br = blockIdx.y;
  const int tid = threadIdx.x;
  const int wave = tid >> 6, lane = tid & 63;
  __shared__ _Float16 Alds[128][40];             // +8 halfs pad (bank spread)
  __shared__ _Float16 Blds[HIDP][40];
  const _Float16* Wb = Wht + (size_t)br * HIDP * KDIM;
  float4v acc[2][13];
#pragma unroll
  for (int mt = 0; mt < 2; ++mt)
#pragma unroll
    for (int nt = 0; nt < 13; ++nt) acc[mt][nt] = (float4v){0.f, 0.f, 0.f, 0.f};

  const int mlo = lane & 15, kq = (lane >> 4) * 8;

  for (int k0 = 0; k0 < KDIM; k0 += 32) {
    __syncthreads();
    // stage A: 128 rows x 32 k (fp32 -> fp16)
#pragma unroll
    for (int p = 0; p < 4; ++p) {
      int idx = tid + p * 256;                   // 0..1023 = 128 rows * 8 float4
      int row = idx >> 3, c4 = idx & 7;
      int grow = m0 + row; if (grow > N_NODES - 1) grow = N_NODES - 1;
      const float4v xv = *(const float4v*)(x + (size_t)grow * FEAT + br * KDIM + k0 + c4 * 4);
      half4 hv = {(_Float16)xv[0], (_Float16)xv[1], (_Float16)xv[2], (_Float16)xv[3]};
      *(half4*)&Alds[row][c4 * 4] = hv;
    }
    // stage B: 208 n-rows x 32 k (already fp16, [n][k] layout)
    for (int idx = tid; idx < HIDP * 4; idx += 256) {
      int n = idx >> 2, c = idx & 3;
      *(half8*)&Blds[n][c * 8] = *(const half8*)(Wb + n * KDIM + k0 + c * 8);
    }
    __syncthreads();
    half8 a0 = *(half8*)&Alds[wave * 32 + mlo][kq];
    half8 a1 = *(half8*)&Alds[wave * 32 + 16 + mlo][kq];
#pragma unroll
    for (int nt = 0; nt < 13; ++nt) {
      half8 b = *(half8*)&Blds[nt * 16 + mlo][kq];
      acc[0][nt] = __builtin_amdgcn_mfma_f32_16x16x32_f16(a0, b, acc[0][nt], 0, 0, 0);
      acc[1][nt] = __builtin_amdgcn_mfma_f32_16x16x32_f16(a1, b, acc[1][nt], 0, 0, 0);
    }
  }
  // epilogue: D-layout n = lane&15, m = (lane>>4)*4 + r
  const int nlo = lane & 15, mq = (lane >> 4) * 4;
#pragma unroll
  for (int mt = 0; mt < 2; ++mt)
#pragma unroll
    for (int nt = 0; nt < 13; ++nt)
#pragma unroll
      for (int r = 0; r < 4; ++r) {
        int row = m0 + wave * 32 + mt * 16 + mq + r;
        if (row < N_NODES)
          hpre[(size_t)row * HID2 + br * HIDP + nt * 16 + nlo] = (_Float16)acc[mt][nt][r];
      }
}

// ---------------- agg1: CSR gather-reduce + bias + relu + fused layer-2 dot ----------
// one wave per dst node; lane L owns 8 contiguous features (chunk of 416)
__global__ __launch_bounds__(64) void agg1_kernel(const int2* __restrict__ ssw,
    const int* __restrict__ row_ptr, const _Float16* __restrict__ hpre,
    const float* __restrict__ b1comb, const float* __restrict__ W2comb,
    float4v* __restrict__ qtab) {
  const int d = blockIdx.x;
  const int lane = threadIdx.x;
  const int e0 = row_ptr[d], e1 = row_ptr[d + 1];
  float acc[8];
#pragma unroll
  for (int j = 0; j < 8; ++j) acc[j] = 0.f;
  if (lane < 52) {
    const _Float16* hp = hpre + lane * 8;
    int e = e0;
    for (; e + 1 < e1; e += 2) {
      int2 s0 = ssw[e], s1 = ssw[e + 1];
      half8 h0 = *(const half8*)(hp + (size_t)s0.x * HID2);
      half8 h1 = *(const half8*)(hp + (size_t)s1.x * HID2);
      float w0 = __int_as_float(s0.y), w1 = __int_as_float(s1.y);
#pragma unroll
      for (int j = 0; j < 8; ++j) acc[j] += w0 * (float)h0[j];
#pragma unroll
      for (int j = 0; j < 8; ++j) acc[j] += w1 * (float)h1[j];
    }
    if (e < e1) {
      int2 s0 = ssw[e];
      half8 h0 = *(const half8*)(hp + (size_t)s0.x * HID2);
      float w0 = __int_as_float(s0.y);
#pragma unroll
      for (int j = 0; j < 8; ++j) acc[j] += w0 * (float)h0[j];
    }
  }
  float p0 = 0.f, p1 = 0.f;
  if (lane < 52) {
#pragma unroll
    for (int j = 0; j < 8; ++j) {
      int col = lane * 8 + j;
      float h = fmaxf(acc[j] + b1comb[col], 0.f);   // h1 (never materialized)
      p0 += h * W2comb[2 * col + 0];
      p1 += h * W2comb[2 * col + 1];
    }
  }
  __shared__ float red0[64], red1[64];
  red0[lane] = p0; red1[lane] = p1;
  __syncthreads();
  if (lane == 0) {
    float q10 = 0, q11 = 0, q20 = 0, q21 = 0;
    for (int l = 0; l < 26; ++l)  { q10 += red0[l]; q11 += red1[l]; }   // branch a (cols 0..207)
    for (int l = 26; l < 52; ++l) { q20 += red0[l]; q21 += red1[l]; }   // branch b (cols 208..415)
    qtab[d] = (float4v){q10, q11, q20, q21};
  }
}

// ---------------- agg2: layer-2 segment_sum + softmax + vote ----------------
// one wave per dst node, 4 nodes per 256-block
__global__ __launch_bounds__(256) void agg2_kernel(const int2* __restrict__ ssw,
    const int* __restrict__ row_ptr, const float4v* __restrict__ qtab,
    const float* __restrict__ b2a, const float* __restrict__ b2b,
    float* __restrict__ out) {
  const int d = blockIdx.x * 4 + (threadIdx.x >> 6);
  const int lane = threadIdx.x & 63;
  const int e0 = row_ptr[d], e1 = row_ptr[d + 1];
  float a0 = 0.f, a1 = 0.f, a2 = 0.f, a3 = 0.f;
  for (int e = e0 + lane; e < e1; e += 64) {
    int2 sw = ssw[e];
    float w = __int_as_float(sw.y);
    float4v q = qtab[sw.x];
    a0 += w * q[0]; a1 += w * q[1]; a2 += w * q[2]; a3 += w * q[3];
  }
#pragma unroll
  for (int off = 32; off > 0; off >>= 1) {
    a0 += __shfl_xor(a0, off);
    a1 += __shfl_xor(a1, off);
    a2 += __shfl_xor(a2, off);
    a3 += __shfl_xor(a3, off);
  }
  if (lane == 0) {
    float za0 = a0 + b2a[0], za1 = a1 + b2a[1];
    float zb0 = a2 + b2b[0], zb1 = a3 + b2b[1];
    float m1 = fmaxf(za0, za1);
    float ea0 = __expf(za0 - m1), ea1 = __expf(za1 - m1);
    float p10 = ea0 / (ea0 + ea1), p11 = ea1 / (ea0 + ea1);
    float m2 = fmaxf(zb0, zb1);
    float eb0 = __expf(zb0 - m2), eb1 = __expf(zb1 - m2);
    float p20 = eb0 / (eb0 + eb1), p21 = eb1 / (eb0 + eb1);
    float v0 = fmaxf(p10, p20), v1 = fmaxf(p11, p21);
    float s = v0 + v1;
    out[d * 2 + 0] = v0 / s;
    out[d * 2 + 1] = v1 / s;
  }
}

extern "C" void kernel_launch(void* const* d_in, const int* in_sizes, int n_in,
                              void* d_out, int out_size, void* d_ws, size_t ws_size,
                              hipStream_t stream) {
  const float* x        = (const float*)d_in[0];
  const int*   edge_src = (const int*)d_in[1];
  const int*   edge_dst = (const int*)d_in[2];
  const float* edge_w   = (const float*)d_in[3];
  const float* W1a = (const float*)d_in[4];
  const float* b1a = (const float*)d_in[5];
  const float* W2a = (const float*)d_in[6];
  const float* b2a = (const float*)d_in[7];
  const float* W1b = (const float*)d_in[8];
  const float* b1b = (const float*)d_in[9];
  const float* W2b = (const float*)d_in[10];
  const float* b2b = (const float*)d_in[11];
  float* out = (float*)d_out;

  char* ws = (char*)d_ws;
  size_t off = 0;
  auto alloc = [&](size_t bytes) -> void* {
    void* p = ws + off;
    off = (off + bytes + 255) & ~(size_t)255;
    return p;
  };
  _Float16* Wht  = (_Float16*)alloc((size_t)2 * HIDP * KDIM * sizeof(_Float16)); // 639 KB
  float* b1comb  = (float*)alloc(HID2 * sizeof(float));
  float* W2comb  = (float*)alloc(HID2 * 2 * sizeof(float));
  int* row_ptr   = (int*)alloc((N_NODES + 1) * sizeof(int));
  int* cnt       = (int*)alloc(N_NODES * sizeof(int));
  int* cnt2      = (int*)alloc(N_NODES * sizeof(int));
  int2* ssw      = (int2*)alloc((size_t)N_EDGES * sizeof(int2));                 // 12.8 MB
  float4v* qtab  = (float4v*)alloc((size_t)N_NODES * sizeof(float4v));           // 800 KB
  _Float16* hpre = (_Float16*)alloc((size_t)N_NODES * HID2 * sizeof(_Float16));  // 41.6 MB
  (void)ws_size; (void)in_sizes; (void)n_in; (void)out_size;

  hipMemsetAsync(cnt,  0, N_NODES * sizeof(int), stream);
  hipMemsetAsync(cnt2, 0, N_NODES * sizeof(int), stream);

  prep_kernel<<<dim3((2 * HIDP * KDIM + 255) / 256), dim3(256), 0, stream>>>(
      W1a, b1a, W2a, W1b, b1b, W2b, Wht, b1comb, W2comb);
  hist_kernel<<<dim3((N_EDGES + 255) / 256), dim3(256), 0, stream>>>(edge_dst, cnt);
  scan_kernel<<<dim3(1), dim3(1024), 0, stream>>>(cnt, row_ptr);
  permute_kernel<<<dim3((N_EDGES + 255) / 256), dim3(256), 0, stream>>>(
      edge_src, edge_dst, edge_w, row_ptr, cnt2, ssw);
  gemm1_kernel<<<dim3((N_NODES + 127) / 128, 2), dim3(256), 0, stream>>>(x, Wht, hpre);
  agg1_kernel<<<dim3(N_NODES), dim3(64), 0, stream>>>(ssw, row_ptr, hpre, b1comb, W2comb, qtab);
  agg2_kernel<<<dim3(N_NODES / 4), dim3(256), 0, stream>>>(ssw, row_ptr, qtab, b2a, b2b, out);
}